// Round 11
// baseline (356.876 us; speedup 1.0000x reference)
//
#include <hip/hip_runtime.h>
#include <hip/hip_bf16.h>

// Problem constants (fixed by reference): B=4, S=2048, DIN=DOUT=4096
constexpr int GM = 8192;   // B*S rows
constexpr int GN = 4096;   // DOUT
constexpr int GK = 4096;   // DIN

constexpr int BM = 256, BN = 128, BK = 32;
constexpr int NT = GK / BK;                     // 128 K-steps
constexpr int SLOT_BYTES = (BM + BN) * BK * 2;  // 24576 B (A 16K + B 8K)
constexpr int LDS_BYTES = 3 * SLOT_BYTES;       // 73728 B -> 2 blocks/CU

using bf16x8 = __attribute__((ext_vector_type(8))) __bf16;
using f32x4  = __attribute__((ext_vector_type(4))) float;

// -------------------- prep: A = bf16(x * in_scale) --------------------
__global__ __launch_bounds__(256) void prep_x_kernel(
    const float* __restrict__ x, const float* __restrict__ iscale,
    __bf16* __restrict__ A) {
  int e = (blockIdx.x * 256 + threadIdx.x) * 8;  // 8 elems/thread
  float4 v0 = *(const float4*)(x + e);
  float4 v1 = *(const float4*)(x + e + 4);
  int k = e & (GK - 1);
  float4 s0 = *(const float4*)(iscale + k);
  float4 s1 = *(const float4*)(iscale + k + 4);
  bf16x8 o;
  o[0] = (__bf16)(v0.x * s0.x);
  o[1] = (__bf16)(v0.y * s0.y);
  o[2] = (__bf16)(v0.z * s0.z);
  o[3] = (__bf16)(v0.w * s0.w);
  o[4] = (__bf16)(v1.x * s1.x);
  o[5] = (__bf16)(v1.y * s1.y);
  o[6] = (__bf16)(v1.z * s1.z);
  o[7] = (__bf16)(v1.w * s1.w);
  *(bf16x8*)(A + e) = o;
}

// -------------------- prep: Wb = bf16(sign(W)) --------------------
__device__ inline float sgnf(float v) {
  return (float)((v > 0.f) - (v < 0.f));
}

__global__ __launch_bounds__(256) void prep_w_kernel(
    const float* __restrict__ w, __bf16* __restrict__ Wb) {
  int e = (blockIdx.x * 256 + threadIdx.x) * 8;
  float4 v0 = *(const float4*)(w + e);
  float4 v1 = *(const float4*)(w + e + 4);
  bf16x8 o;
  o[0] = (__bf16)sgnf(v0.x);
  o[1] = (__bf16)sgnf(v0.y);
  o[2] = (__bf16)sgnf(v0.z);
  o[3] = (__bf16)sgnf(v0.w);
  o[4] = (__bf16)sgnf(v1.x);
  o[5] = (__bf16)sgnf(v1.y);
  o[6] = (__bf16)sgnf(v1.z);
  o[7] = (__bf16)sgnf(v1.w);
  *(bf16x8*)(Wb + e) = o;
}

// -------------------- GEMM: C[m][n] = sum_k A[m][k]*Wb[n][k] --------------------
// TWO-BLOCKS-PER-CU regime. 256x128 tile, BK=32, 256 threads (4 waves =
// 2M x 2N, wave tile 128x64, 16x16x32 MFMA, acc[8][4]). LDS: 3-slot ring
// x 24 KiB = 72 KiB -> 2 independent blocks co-resident per CU
// (launch_bounds(256,2)). When one block sits in its barrier/vmcnt drain,
// the other block's waves keep the MFMA pipe fed (m114 overlap) — the
// 1-block-per-CU lockstep was the invariant across R3-R10's ~50% plateau.
// Per K-step: STAGE(t+2 -> slot[(t+2)%3], 6 gload_lds) at top; 12 ds_read
// (av[8], bv[4]); 32 MFMA (compiler interleaves via fine lgkmcnt);
// vmcnt(6) (drains t+1, keeps t+2's 6 in flight); 1 barrier.
// Ring safety (R3-proven): slot staged at iter t was last read at iter t-1,
// separated by iter t-1's end barrier.
// Swizzle (R3's exact BK=32 pattern, measured 0 conflicts): 16-B chunk c of
// row r holds K-group c^((r>>1)&3); stage pre-permutes the global source
// column (involution), reads XOR the chunk index.
__device__ inline void gload16(const __bf16* g, const __bf16* l) {
  __builtin_amdgcn_global_load_lds(
      (const __attribute__((address_space(1))) void*)g,
      (__attribute__((address_space(3))) void*)l, 16, 0, 0);
}

__global__ __launch_bounds__(256, 2) void gemm_bt(
    const __bf16* __restrict__ A, const __bf16* __restrict__ B,
    float* __restrict__ C) {
  extern __shared__ __bf16 lds[];  // 3 slots x (A 8192 + B 4096 elems)

  // Square XCD chunking: XCD x owns 8 brows x 16 bcols; co-resident half is
  // 8x8 (A 16 MB + B 8 MB per XCD; L3 absorbs — ~200 MB fetch in R3-R8).
  int bid = blockIdx.x;            // 0..1023
  int x = bid & 7, idx = bid >> 3; // 128 blocks per XCD
  int brow = ((x & 3) << 3) | (idx & 7);    // 0..31
  int bcol = ((x >> 2) << 4) | (idx >> 3);  // 0..31

  int tid = threadIdx.x, wid = tid >> 6, lane = tid & 63;
  int wm = wid & 1, wn = wid >> 1;         // 2M x 2N waves
  int lrow = lane & 15, lkhi = lane >> 4;
  int rchunk = lkhi ^ ((lrow >> 1) & 3);   // swizzled 16-B chunk on read

  const __bf16* Ab = A + (size_t)(brow * BM) * GK;
  const __bf16* Bb = B + (size_t)(bcol * BN) * GK;

  const char* ldsc = (const char*)lds;
  // per-lane byte offsets within a slot (A at 0 [256 rows][64 B],
  // B at 16384 [128 rows][64 B]); + mi*1024 / + ni*1024 (16 rows each)
  const int offA = (wm * 128 + lrow) * 64 + rchunk * 16;
  const int offB = 16384 + (wn * 64 + lrow) * 64 + rchunk * 16;

  // stage-side: thread t covers row t>>2, 16-B chunk t&3; source K-group
  // pre-swizzled (involution): gchunk = (t&3) ^ ((t>>3)&3); row+64li keeps
  // the same parity bits ((r>>1)&3 invariant under +64).
  int grow = tid >> 2;                              // 0..63
  int gcol = ((tid & 3) ^ ((tid >> 3) & 3)) * 8;    // elems

  auto STAGE = [&](int kt, int si) {
    const __bf16* sA = Ab + (size_t)grow * GK + kt * BK + gcol;
    const __bf16* dA = lds + si * (SLOT_BYTES / 2) + tid * 8;
#pragma unroll
    for (int li = 0; li < 4; ++li)   // A: 256 rows, 64 per issue
      gload16(sA + (size_t)(li * 64) * GK, dA + li * 2048);
    const __bf16* sB = Bb + (size_t)grow * GK + kt * BK + gcol;
#pragma unroll
    for (int li = 0; li < 2; ++li)   // B: 128 rows
      gload16(sB + (size_t)(li * 64) * GK, dA + 8192 + li * 2048);
  };

  f32x4 acc[8][4] = {};

  // prologue: tiles 0,1 staged; tile 0 landed (6 newest stay in flight)
  STAGE(0, 0);
  STAGE(1, 1);
  asm volatile("s_waitcnt vmcnt(6)" ::: "memory");
  __builtin_amdgcn_s_barrier();

  int bc = 0, bs = 2;
  for (int t = 0; t < NT; ++t) {
    if (t + 2 < NT) STAGE(t + 2, bs);

    const char* sl = ldsc + bc * SLOT_BYTES;
    bf16x8 av[8], bv[4];
#pragma unroll
    for (int mi = 0; mi < 8; ++mi)
      av[mi] = *(const bf16x8*)(sl + offA + mi * 1024);
#pragma unroll
    for (int ni = 0; ni < 4; ++ni)
      bv[ni] = *(const bf16x8*)(sl + offB + ni * 1024);

    __builtin_amdgcn_s_setprio(1);
#pragma unroll
    for (int mi = 0; mi < 8; ++mi)
#pragma unroll
      for (int ni = 0; ni < 4; ++ni)
        acc[mi][ni] = __builtin_amdgcn_mfma_f32_16x16x32_bf16(
            av[mi], bv[ni], acc[mi][ni], 0, 0, 0);
    __builtin_amdgcn_s_setprio(0);

    __builtin_amdgcn_sched_barrier(0);
    if (t < NT - 1) {
      if (t + 2 < NT) asm volatile("s_waitcnt vmcnt(6)" ::: "memory");
      else            asm volatile("s_waitcnt vmcnt(0)" ::: "memory");
      __builtin_amdgcn_s_barrier();
    }
    bc = (bc == 2) ? 0 : bc + 1;
    bs = (bs == 2) ? 0 : bs + 1;
  }

  // epilogue: C/D layout (16x16x32 bf16): col = lane&15, row = (lane>>4)*4 + r
  int crow0 = brow * BM + wm * 128;
  int ccol0 = bcol * BN + wn * 64;
#pragma unroll
  for (int mi = 0; mi < 8; ++mi)
#pragma unroll
    for (int ni = 0; ni < 4; ++ni) {
      int col = ccol0 + ni * 16 + lrow;
#pragma unroll
      for (int r = 0; r < 4; ++r) {
        int row = crow0 + mi * 16 + lkhi * 4 + r;
        C[(size_t)row * GN + col] = acc[mi][ni][r];
      }
    }
}

// -------------------- fused out_scale/bias + LayerNorm (in place) --------------------
__global__ __launch_bounds__(256) void ln_fuse(
    float* __restrict__ h, const float* __restrict__ os,
    const float* __restrict__ bs, const float* __restrict__ g,
    const float* __restrict__ be) {
  constexpr int N = GN;  // 4096
  int row = blockIdx.x;
  float* hr = h + (size_t)row * N;
  int t = threadIdx.x;

  float v[16];
  float sum = 0.f, ssq = 0.f;
#pragma unroll
  for (int c = 0; c < 4; ++c) {
    int idx = c * 1024 + t * 4;
    float4 hv = *(const float4*)(hr + idx);
    float4 sv = *(const float4*)(os + idx);
    float4 bv = *(const float4*)(bs + idx);
    float a0 = hv.x * sv.x + bv.x;
    float a1 = hv.y * sv.y + bv.y;
    float a2 = hv.z * sv.z + bv.z;
    float a3 = hv.w * sv.w + bv.w;
    v[c * 4 + 0] = a0; v[c * 4 + 1] = a1; v[c * 4 + 2] = a2; v[c * 4 + 3] = a3;
    sum += a0 + a1 + a2 + a3;
    ssq += a0 * a0 + a1 * a1 + a2 * a2 + a3 * a3;
  }

  // wave64 reduce
#pragma unroll
  for (int off = 32; off > 0; off >>= 1) {
    sum += __shfl_down(sum, off);
    ssq += __shfl_down(ssq, off);
  }
  __shared__ float rs[8];
  int wid = t >> 6, lane = t & 63;
  if (lane == 0) { rs[wid] = sum; rs[4 + wid] = ssq; }
  __syncthreads();
  sum = rs[0] + rs[1] + rs[2] + rs[3];
  ssq = rs[4] + rs[5] + rs[6] + rs[7];

  float mean = sum * (1.f / N);
  float var = ssq * (1.f / N) - mean * mean;
  float rstd = rsqrtf(var + 1e-5f);

#pragma unroll
  for (int c = 0; c < 4; ++c) {
    int idx = c * 1024 + t * 4;
    float4 gv = *(const float4*)(g + idx);
    float4 bev = *(const float4*)(be + idx);
    float4 o;
    o.x = (v[c * 4 + 0] - mean) * rstd * gv.x + bev.x;
    o.y = (v[c * 4 + 1] - mean) * rstd * gv.y + bev.y;
    o.z = (v[c * 4 + 2] - mean) * rstd * gv.z + bev.z;
    o.w = (v[c * 4 + 3] - mean) * rstd * gv.w + bev.w;
    *(float4*)(hr + idx) = o;
  }
}

extern "C" void kernel_launch(void* const* d_in, const int* in_sizes, int n_in,
                              void* d_out, int out_size, void* d_ws, size_t ws_size,
                              hipStream_t stream) {
  const float* x      = (const float*)d_in[0];  // [4,2048,4096]
  const float* w      = (const float*)d_in[1];  // [4096,4096]
  const float* iscale = (const float*)d_in[2];  // [4096]
  const float* oscale = (const float*)d_in[3];  // [4096]
  const float* bias   = (const float*)d_in[4];  // [4096]
  const float* gamma  = (const float*)d_in[5];  // [4096]
  const float* beta   = (const float*)d_in[6];  // [4096]
  float* out = (float*)d_out;                   // [8192,4096] f32

  __bf16* Abf = (__bf16*)d_ws;                                   // 67 MB
  __bf16* Wbf = (__bf16*)((char*)d_ws + (size_t)GM * GK * 2);    // 33.5 MB

  (void)hipFuncSetAttribute((const void*)gemm_bt,
                            hipFuncAttributeMaxDynamicSharedMemorySize, LDS_BYTES);

  prep_x_kernel<<<(GM * GK) / (256 * 8), 256, 0, stream>>>(x, iscale, Abf);
  prep_w_kernel<<<(GN * GK) / (256 * 8), 256, 0, stream>>>(w, Wbf);
  gemm_bt<<<(GM / BM) * (GN / BN), 256, LDS_BYTES, stream>>>(Abf, Wbf, out);
  ln_fuse<<<GM, 256, 0, stream>>>(out, oscale, bias, gamma, beta);
}

// Round 12
// 338.436 us; speedup vs baseline: 1.0545x; 1.0545x over previous
//
#include <hip/hip_runtime.h>
#include <hip/hip_bf16.h>

// Problem constants (fixed by reference): B=4, S=2048, DIN=DOUT=4096
constexpr int GM = 8192;   // B*S rows
constexpr int GN = 4096;   // DOUT
constexpr int GK = 4096;   // DIN

constexpr int BM = 256, BN = 256, BK = 64;
constexpr int NSTEP = GK / BK;              // 64 K-steps
constexpr int LDS_BYTES = 2 * BM * BK * 2;  // 65536: A-only double buffer

using bf16x8 = __attribute__((ext_vector_type(8))) __bf16;
using f32x4  = __attribute__((ext_vector_type(4))) float;

// -------------------- prep: A = bf16(x * in_scale) --------------------
__global__ __launch_bounds__(256) void prep_x_kernel(
    const float* __restrict__ x, const float* __restrict__ iscale,
    __bf16* __restrict__ A) {
  int e = (blockIdx.x * 256 + threadIdx.x) * 8;  // 8 elems/thread
  float4 v0 = *(const float4*)(x + e);
  float4 v1 = *(const float4*)(x + e + 4);
  int k = e & (GK - 1);
  float4 s0 = *(const float4*)(iscale + k);
  float4 s1 = *(const float4*)(iscale + k + 4);
  bf16x8 o;
  o[0] = (__bf16)(v0.x * s0.x);
  o[1] = (__bf16)(v0.y * s0.y);
  o[2] = (__bf16)(v0.z * s0.z);
  o[3] = (__bf16)(v0.w * s0.w);
  o[4] = (__bf16)(v1.x * s1.x);
  o[5] = (__bf16)(v1.y * s1.y);
  o[6] = (__bf16)(v1.z * s1.z);
  o[7] = (__bf16)(v1.w * s1.w);
  *(bf16x8*)(A + e) = o;
}

// -------------------- prep: Wb8 = high byte of bf16(sign(W)), fragmented ---
// Wb8[((rt*128 + kt)*64 + lane)*8 + e] = sb(W[rt*16 + (lane&15)]
//                                            [kt*32 + (lane>>4)*8 + e])
// sb: +1 -> 0x3F, -1 -> 0xBF, 0 -> 0x00  (bf16 reconstructed as (sb<<8)|0x80;
// the w==0 case yields 0x0080 = 4.6e-41, numerically harmless).
// A wave's B-fragment (16 cols x 32 k) is ONE contiguous 512-B load.
__global__ __launch_bounds__(256) void prep_w_kernel(
    const float* __restrict__ w, unsigned char* __restrict__ Wb8) {
  int T = blockIdx.x * 256 + threadIdx.x;   // one fragment slice (8 bytes)
  int lane = T & 63;
  int kt = (T >> 6) & 127;
  int rt = T >> 13;
  int r = rt * 16 + (lane & 15);
  int k = kt * 32 + (lane >> 4) * 8;
  const float* src = w + (size_t)r * GK + k;
  float4 v0 = *(const float4*)(src);
  float4 v1 = *(const float4*)(src + 4);
  auto sb = [](float v) -> unsigned int {
    return v > 0.f ? 0x3Fu : (v < 0.f ? 0xBFu : 0x00u);
  };
  uint2 o;
  o.x = sb(v0.x) | (sb(v0.y) << 8) | (sb(v0.z) << 16) | (sb(v0.w) << 24);
  o.y = sb(v1.x) | (sb(v1.y) << 8) | (sb(v1.z) << 16) | (sb(v1.w) << 24);
  *(uint2*)(Wb8 + (size_t)T * 8) = o;
}

// -------------------- GEMM: C[m][n] = sum_k A[m][k]*sign(W)[n][k] ----------
// BYTE-B structure (R9 skeleton, B volume halved + L2-resident).
// 256x256 tile, BK=64, 512 threads (2M x 4N waves, wave tile 128x64).
// LDS holds ONLY A (2 x 32 KiB). B loads global->reg as raw sign-bytes
// (8 x uint2 per wave per K-step = 512 B coalesced each), double-buffered
// one K-step ahead (rawE/rawO named sets); expanded to bf16 at step top
// via (byte<<8)|0x80 bit-ops (~6 VALU per 4 elems).
// Volume model (the R3-R11 invariant binder): staged/fetched bytes were
// grid x (BM+BN) x K x 2B = 2.1 GB at L3-class BW ~= 240 us. Now: A 1.05 GB
// (L3, ~105 us < 132 us MFMA floor) + B 0.53 GB L2-RESIDENT (per-XCD panel
// 1.05 MB vs 4 MB L2; R9's 2.1 MB-bf16 x2 bcols = 4.2 MB thrashed -> 553 MB
// HBM fetch).
// Sync (identical VMEM op counts to R9, analysis carries verbatim):
// even step t: STAGE_A(t+1->buf1)[4]; CVT(rawE); ds_read a0(8); 32 MFMA;
// ds_read a4(8); 32 MFMA; LOADB(t+2->rawE)[8]; vmcnt(8); barrier.
// Queue at boundary: A(t+1)[4]+B(t+2)[8] outstanding; vmcnt(8) retires
// A(t+1) and all older (B(t+1) proven retired at the t-1 boundary ->
// CVT at step top reads landed data). WAR: STAGE_A(t+1) targets the buffer
// whose readers passed the t-1 barrier; raws are register-private.
// A-swizzle (R9-measured 0 conflicts): 16-B chunk c of row r holds K-group
// c^(r&7); stage pre-permutes source col, reads XOR the chunk.
// XCD map: XCD x covers all 32 brows x bcols {2x,2x+1}; per round all 32
// blocks share ONE bcol -> B tile re-read 32x from L2; brows mirror across
// XCDs -> A tiles L3-shared 8-way.
__device__ inline void gload16(const __bf16* g, const __bf16* l) {
  __builtin_amdgcn_global_load_lds(
      (const __attribute__((address_space(1))) void*)g,
      (__attribute__((address_space(3))) void*)l, 16, 0, 0);
}

__global__ __launch_bounds__(512, 2) void gemm_bt(
    const __bf16* __restrict__ A, const unsigned char* __restrict__ Wb8,
    float* __restrict__ C) {
  extern __shared__ __bf16 lds[];  // 2 x 16384 elems, A only

  int bid = blockIdx.x;            // 0..511
  int x = bid & 7, idx = bid >> 3; // 64 blocks per XCD
  int brow = idx & 31;             // 0..31
  int bcol = (x << 1) | (idx >> 5);  // 0..15

  int tid = threadIdx.x, wid = tid >> 6, lane = tid & 63;
  int wm = wid & 1, wn = wid >> 1;   // 2M x 4N waves
  int lrow = lane & 15, lkhi = lane >> 4;

  const __bf16* Ab = A + (size_t)(brow * BM) * GK;

  // read-side swizzled chunk offsets (bytes within 128-B A row)
  int xr = lrow & 7;
  int offk0 = (lkhi ^ xr) * 16;
  int offk1 = ((4 + lkhi) ^ xr) * 16;
  const char* ldsc = (const char*)lds;
  int avbase = (wm * 128 + lrow) * 128;  // + mi*2048 + offk; bufs at 0/32768 B

  // A-stage: thread t covers row (t>>3)+64*li, chunk t&7, pre-swizzled src
  int grow = tid >> 3;
  int gcol = ((tid & 7) ^ (grow & 7)) * 8;

  // B: per-lane base into byte-fragmented Wb8; frag (ni, kt=2t+kk) at
  // + ni*65536 + (2t+kk)*512 bytes (rt = bcol*16 + wn*4 + ni)
  const unsigned char* bw = Wb8 + (size_t)(bcol * 16 + wn * 4) * 65536 + lane * 8;

  auto STAGE_A = [&](int kstep, int bufE) {
    const __bf16* s = Ab + (size_t)grow * GK + kstep * BK + gcol;
    const __bf16* d = lds + bufE + tid * 8;
    gload16(s, d);
    gload16(s + (size_t)64 * GK, d + 4096);
    gload16(s + (size_t)128 * GK, d + 8192);
    gload16(s + (size_t)192 * GK, d + 12288);
  };

  uint2 rawE[8], rawO[8];  // [ni*2+kk] raw sign-bytes, double-buffered
  auto LOADB = [&](int tt, uint2 (&raw)[8]) {
#pragma unroll
    for (int ni = 0; ni < 4; ++ni) {
      raw[ni * 2 + 0] = *(const uint2*)(bw + ni * 65536 + (2 * tt + 0) * 512);
      raw[ni * 2 + 1] = *(const uint2*)(bw + ni * 65536 + (2 * tt + 1) * 512);
    }
  };

  bf16x8 bv[4][2];
  auto CVT = [&](const uint2 (&raw)[8]) {
#pragma unroll
    for (int ni = 0; ni < 4; ++ni)
#pragma unroll
      for (int kk = 0; kk < 2; ++kk) {
        uint2 r8 = raw[ni * 2 + kk];
        union { unsigned int u[4]; bf16x8 v; } cv;
        cv.u[0] = ((r8.x & 0x000000FFu) << 8) | ((r8.x & 0x0000FF00u) << 16) | 0x00800080u;
        cv.u[1] = ((r8.x & 0x00FF0000u) >> 8) | (r8.x & 0xFF000000u)         | 0x00800080u;
        cv.u[2] = ((r8.y & 0x000000FFu) << 8) | ((r8.y & 0x0000FF00u) << 16) | 0x00800080u;
        cv.u[3] = ((r8.y & 0x00FF0000u) >> 8) | (r8.y & 0xFF000000u)         | 0x00800080u;
        bv[ni][kk] = cv.v;
      }
  };

  f32x4 acc[8][4] = {};

  // prologue: A(0)->buf0; B(0)->rawE; B(1)->rawO; vmcnt(8) drains A(0)+B(0)
  STAGE_A(0, 0);
  LOADB(0, rawE);
  LOADB(1, rawO);
  asm volatile("s_waitcnt vmcnt(8)" ::: "memory");
  __builtin_amdgcn_s_barrier();

  for (int t = 0; t < NSTEP; t += 2) {
    // ================= even K-step t (buf0, rawE) =================
    {
      if (t + 1 < NSTEP) STAGE_A(t + 1, 16384);
      CVT(rawE);
      bf16x8 a[4][2];
#pragma unroll
      for (int mi = 0; mi < 4; ++mi) {
        a[mi][0] = *(const bf16x8*)(ldsc + avbase + mi * 2048 + offk0);
        a[mi][1] = *(const bf16x8*)(ldsc + avbase + mi * 2048 + offk1);
      }
      __builtin_amdgcn_s_setprio(1);
#pragma unroll
      for (int mi = 0; mi < 4; ++mi)
#pragma unroll
        for (int ni = 0; ni < 4; ++ni)
#pragma unroll
          for (int kk = 0; kk < 2; ++kk)
            acc[mi][ni] = __builtin_amdgcn_mfma_f32_16x16x32_bf16(
                a[mi][kk], bv[ni][kk], acc[mi][ni], 0, 0, 0);
      __builtin_amdgcn_s_setprio(0);
#pragma unroll
      for (int mi = 0; mi < 4; ++mi) {
        a[mi][0] = *(const bf16x8*)(ldsc + avbase + (4 + mi) * 2048 + offk0);
        a[mi][1] = *(const bf16x8*)(ldsc + avbase + (4 + mi) * 2048 + offk1);
      }
      __builtin_amdgcn_s_setprio(1);
#pragma unroll
      for (int mi = 0; mi < 4; ++mi)
#pragma unroll
        for (int ni = 0; ni < 4; ++ni)
#pragma unroll
          for (int kk = 0; kk < 2; ++kk)
            acc[4 + mi][ni] = __builtin_amdgcn_mfma_f32_16x16x32_bf16(
                a[mi][kk], bv[ni][kk], acc[4 + mi][ni], 0, 0, 0);
      __builtin_amdgcn_s_setprio(0);
      if (t + 2 < NSTEP) LOADB(t + 2, rawE);
      __builtin_amdgcn_sched_barrier(0);
      if (t + 2 < NSTEP) asm volatile("s_waitcnt vmcnt(8)" ::: "memory");
      else               asm volatile("s_waitcnt vmcnt(0)" ::: "memory");
      __builtin_amdgcn_s_barrier();
    }
    // ================= odd K-step t+1 (buf1, rawO) =================
    {
      if (t + 2 < NSTEP) STAGE_A(t + 2, 0);
      CVT(rawO);
      bf16x8 a[4][2];
#pragma unroll
      for (int mi = 0; mi < 4; ++mi) {
        a[mi][0] = *(const bf16x8*)(ldsc + 32768 + avbase + mi * 2048 + offk0);
        a[mi][1] = *(const bf16x8*)(ldsc + 32768 + avbase + mi * 2048 + offk1);
      }
      __builtin_amdgcn_s_setprio(1);
#pragma unroll
      for (int mi = 0; mi < 4; ++mi)
#pragma unroll
        for (int ni = 0; ni < 4; ++ni)
#pragma unroll
          for (int kk = 0; kk < 2; ++kk)
            acc[mi][ni] = __builtin_amdgcn_mfma_f32_16x16x32_bf16(
                a[mi][kk], bv[ni][kk], acc[mi][ni], 0, 0, 0);
      __builtin_amdgcn_s_setprio(0);
#pragma unroll
      for (int mi = 0; mi < 4; ++mi) {
        a[mi][0] = *(const bf16x8*)(ldsc + 32768 + avbase + (4 + mi) * 2048 + offk0);
        a[mi][1] = *(const bf16x8*)(ldsc + 32768 + avbase + (4 + mi) * 2048 + offk1);
      }
      __builtin_amdgcn_s_setprio(1);
#pragma unroll
      for (int mi = 0; mi < 4; ++mi)
#pragma unroll
        for (int ni = 0; ni < 4; ++ni)
#pragma unroll
          for (int kk = 0; kk < 2; ++kk)
            acc[4 + mi][ni] = __builtin_amdgcn_mfma_f32_16x16x32_bf16(
                a[mi][kk], bv[ni][kk], acc[4 + mi][ni], 0, 0, 0);
      __builtin_amdgcn_s_setprio(0);
      if (t + 3 < NSTEP) LOADB(t + 3, rawO);
      __builtin_amdgcn_sched_barrier(0);
      if (t + 3 < NSTEP) {
        asm volatile("s_waitcnt vmcnt(8)" ::: "memory");
        __builtin_amdgcn_s_barrier();
      } else if (t + 2 < NSTEP) {
        asm volatile("s_waitcnt vmcnt(0)" ::: "memory");
        __builtin_amdgcn_s_barrier();
      }
      // t+1 == NSTEP-1: fall through to epilogue
    }
  }

  // epilogue: C/D layout (16x16x32 bf16): col = lane&15, row = (lane>>4)*4 + r
  int crow0 = brow * BM + wm * 128;
  int ccol0 = bcol * BN + wn * 64;
#pragma unroll
  for (int mi = 0; mi < 8; ++mi)
#pragma unroll
    for (int ni = 0; ni < 4; ++ni) {
      int col = ccol0 + ni * 16 + lrow;
#pragma unroll
      for (int r = 0; r < 4; ++r) {
        int row = crow0 + mi * 16 + lkhi * 4 + r;
        C[(size_t)row * GN + col] = acc[mi][ni][r];
      }
    }
}

// -------------------- fused out_scale/bias + LayerNorm (in place) --------------------
__global__ __launch_bounds__(256) void ln_fuse(
    float* __restrict__ h, const float* __restrict__ os,
    const float* __restrict__ bs, const float* __restrict__ g,
    const float* __restrict__ be) {
  constexpr int N = GN;  // 4096
  int row = blockIdx.x;
  float* hr = h + (size_t)row * N;
  int t = threadIdx.x;

  float v[16];
  float sum = 0.f, ssq = 0.f;
#pragma unroll
  for (int c = 0; c < 4; ++c) {
    int idx = c * 1024 + t * 4;
    float4 hv = *(const float4*)(hr + idx);
    float4 sv = *(const float4*)(os + idx);
    float4 bv = *(const float4*)(bs + idx);
    float a0 = hv.x * sv.x + bv.x;
    float a1 = hv.y * sv.y + bv.y;
    float a2 = hv.z * sv.z + bv.z;
    float a3 = hv.w * sv.w + bv.w;
    v[c * 4 + 0] = a0; v[c * 4 + 1] = a1; v[c * 4 + 2] = a2; v[c * 4 + 3] = a3;
    sum += a0 + a1 + a2 + a3;
    ssq += a0 * a0 + a1 * a1 + a2 * a2 + a3 * a3;
  }

  // wave64 reduce
#pragma unroll
  for (int off = 32; off > 0; off >>= 1) {
    sum += __shfl_down(sum, off);
    ssq += __shfl_down(ssq, off);
  }
  __shared__ float rs[8];
  int wid = t >> 6, lane = t & 63;
  if (lane == 0) { rs[wid] = sum; rs[4 + wid] = ssq; }
  __syncthreads();
  sum = rs[0] + rs[1] + rs[2] + rs[3];
  ssq = rs[4] + rs[5] + rs[6] + rs[7];

  float mean = sum * (1.f / N);
  float var = ssq * (1.f / N) - mean * mean;
  float rstd = rsqrtf(var + 1e-5f);

#pragma unroll
  for (int c = 0; c < 4; ++c) {
    int idx = c * 1024 + t * 4;
    float4 gv = *(const float4*)(g + idx);
    float4 bev = *(const float4*)(be + idx);
    float4 o;
    o.x = (v[c * 4 + 0] - mean) * rstd * gv.x + bev.x;
    o.y = (v[c * 4 + 1] - mean) * rstd * gv.y + bev.y;
    o.z = (v[c * 4 + 2] - mean) * rstd * gv.z + bev.z;
    o.w = (v[c * 4 + 3] - mean) * rstd * gv.w + bev.w;
    *(float4*)(hr + idx) = o;
  }
}

extern "C" void kernel_launch(void* const* d_in, const int* in_sizes, int n_in,
                              void* d_out, int out_size, void* d_ws, size_t ws_size,
                              hipStream_t stream) {
  const float* x      = (const float*)d_in[0];  // [4,2048,4096]
  const float* w      = (const float*)d_in[1];  // [4096,4096]
  const float* iscale = (const float*)d_in[2];  // [4096]
  const float* oscale = (const float*)d_in[3];  // [4096]
  const float* bias   = (const float*)d_in[4];  // [4096]
  const float* gamma  = (const float*)d_in[5];  // [4096]
  const float* beta   = (const float*)d_in[6];  // [4096]
  float* out = (float*)d_out;                   // [8192,4096] f32

  __bf16* Abf = (__bf16*)d_ws;                                       // 67 MB
  unsigned char* Wb8 = (unsigned char*)d_ws + (size_t)GM * GK * 2;   // 16.8 MB

  (void)hipFuncSetAttribute((const void*)gemm_bt,
                            hipFuncAttributeMaxDynamicSharedMemorySize, LDS_BYTES);

  prep_x_kernel<<<(GM * GK) / (256 * 8), 256, 0, stream>>>(x, iscale, Abf);
  prep_w_kernel<<<(GN * GK) / (256 * 8), 256, 0, stream>>>(w, Wb8);
  gemm_bt<<<(GM / BM) * (GN / BN), 512, LDS_BYTES, stream>>>(Abf, Wb8, out);
  ln_fuse<<<GM, 256, 0, stream>>>(out, oscale, bias, gamma, beta);
}

// Round 13
// 299.282 us; speedup vs baseline: 1.1924x; 1.1308x over previous
//
#include <hip/hip_runtime.h>
#include <hip/hip_bf16.h>

// Problem constants (fixed by reference): B=4, S=2048, DIN=DOUT=4096
constexpr int GM = 8192;   // B*S rows
constexpr int GN = 4096;   // DOUT
constexpr int GK = 4096;   // DIN

constexpr int BM = 256, BN = 256, BK = 64;
constexpr int NSTEP = GK / BK;   // 64 K-steps
constexpr int IT = NSTEP / 2;    // 32 iterations, 2 K-steps each
constexpr int LDS_BYTES = 2 * (BM + BN) * BK * 2;  // 131072 = 128 KiB

using bf16x8 = __attribute__((ext_vector_type(8))) __bf16;
using f32x4  = __attribute__((ext_vector_type(4))) float;

// -------------------- prep: A = bf16(x * in_scale) --------------------
__global__ __launch_bounds__(256) void prep_x_kernel(
    const float* __restrict__ x, const float* __restrict__ iscale,
    __bf16* __restrict__ A) {
  int e = (blockIdx.x * 256 + threadIdx.x) * 8;  // 8 elems/thread
  float4 v0 = *(const float4*)(x + e);
  float4 v1 = *(const float4*)(x + e + 4);
  int k = e & (GK - 1);
  float4 s0 = *(const float4*)(iscale + k);
  float4 s1 = *(const float4*)(iscale + k + 4);
  bf16x8 o;
  o[0] = (__bf16)(v0.x * s0.x);
  o[1] = (__bf16)(v0.y * s0.y);
  o[2] = (__bf16)(v0.z * s0.z);
  o[3] = (__bf16)(v0.w * s0.w);
  o[4] = (__bf16)(v1.x * s1.x);
  o[5] = (__bf16)(v1.y * s1.y);
  o[6] = (__bf16)(v1.z * s1.z);
  o[7] = (__bf16)(v1.w * s1.w);
  *(bf16x8*)(A + e) = o;
}

// -------------------- prep: Wb = bf16(sign(W)) --------------------
__device__ inline float sgnf(float v) {
  return (float)((v > 0.f) - (v < 0.f));
}

__global__ __launch_bounds__(256) void prep_w_kernel(
    const float* __restrict__ w, __bf16* __restrict__ Wb) {
  int e = (blockIdx.x * 256 + threadIdx.x) * 8;
  float4 v0 = *(const float4*)(w + e);
  float4 v1 = *(const float4*)(w + e + 4);
  bf16x8 o;
  o[0] = (__bf16)sgnf(v0.x);
  o[1] = (__bf16)sgnf(v0.y);
  o[2] = (__bf16)sgnf(v0.z);
  o[3] = (__bf16)sgnf(v0.w);
  o[4] = (__bf16)sgnf(v1.x);
  o[5] = (__bf16)sgnf(v1.y);
  o[6] = (__bf16)sgnf(v1.z);
  o[7] = (__bf16)sgnf(v1.w);
  *(bf16x8*)(Wb + e) = o;
}

// -------------------- GEMM: C[m][n] = sum_k A[m][k]*Wb[n][k] --------------------
// R8's m201-faithful 8-phase schedule, DE-PINNED (m141/m201 lesson: only the
// rule-18 sched_barrier after lgkmcnt(0) is load-bearing; all ds_reads are
// already phase-ordered by the memory-clobbered waitcnt asm, so the other
// 16 sched_barriers per iteration only blocked useful MFMA sinking).
// 256x256 tile, BK=64, 512 threads (2M x 4N waves, wave tile 128x64).
// LDS: 2 buffers x [A0|A1|B0|B1] x 16 KiB. Phases per iteration:
//   P1: reads a0(8)+b0(4) [lgkmcnt(8) throttle]; stage (o):A1  | QUAD(0,0)
//   P2: reads b2(4)                                            | QUAD(0,2)
//   P3: reads a4(8); stage (2j+2):B0,B1                        | QUAD(4,0)
//   P4: stage (2j+2):A0; QUAD(4,2) + vmcnt(6) + barrier
//   P5-P8: mirror on buf1, staging (2j+2):A1 / (2j+3):B0,B1 / (2j+3):A0.
// vmcnt(6) retire-set verified by load counting (14 outstanding -> retire 8
// = exactly the next-consumed step). WAR: every region's stage phase follows
// its last-read phase across a phase barrier.
// EPILOGUE: h stored as bf16 into the SECOND HALF of each f32 output row
// slot of d_out (byte row*16384 + 8192) — halves the C-write; ln_fuse reads
// it back and overwrites the full slot with f32 (block-local overlap only).
// Swizzle (both sides, 0 conflicts measured R3-R9): 16-B chunk c of row r
// holds K-group c^(r&7); stage pre-permutes source col, reads XOR chunk.
__device__ inline void gload16(const __bf16* g, const __bf16* l) {
  __builtin_amdgcn_global_load_lds(
      (const __attribute__((address_space(1))) void*)g,
      (__attribute__((address_space(3))) void*)l, 16, 0, 0);
}

#define PHASE_SYNC()                                    \
  __builtin_amdgcn_s_barrier();                         \
  asm volatile("s_waitcnt lgkmcnt(0)" ::: "memory");    \
  __builtin_amdgcn_sched_barrier(0);                    \
  __builtin_amdgcn_s_setprio(1);

#define PHASE_END()                                     \
  __builtin_amdgcn_s_setprio(0);                        \
  __builtin_amdgcn_s_barrier();

#define QUAD(AV, BV, MO, NO)                                                 \
  {                                                                          \
    _Pragma("unroll") for (int mi = 0; mi < 4; ++mi)                         \
      _Pragma("unroll") for (int ni = 0; ni < 2; ++ni)                       \
        _Pragma("unroll") for (int kk = 0; kk < 2; ++kk)                     \
            acc[(MO) + mi][(NO) + ni] =                                      \
                __builtin_amdgcn_mfma_f32_16x16x32_bf16(                     \
                    AV[mi][kk], BV[ni][kk], acc[(MO) + mi][(NO) + ni],       \
                    0, 0, 0);                                                \
  }

__global__ __launch_bounds__(512, 2) void gemm_bt(
    const __bf16* __restrict__ A, const __bf16* __restrict__ B,
    float* __restrict__ C) {
  extern __shared__ __bf16 lds[];  // 2 x 64 KiB buffers

  // Square XCD chunking (FETCH ~197 MB measured R3-R8)
  int bid = blockIdx.x;            // 0..511
  int x = bid & 7, idx = bid >> 3;
  int brow = ((x & 3) << 3) | (idx & 7);   // 0..31
  int bcol = ((x >> 2) << 3) | (idx >> 3); // 0..15

  int tid = threadIdx.x, wid = tid >> 6, lane = tid & 63;
  int wm = wid & 1, wn = wid >> 1;         // 2M x 4N waves
  int lrow = lane & 15, lkhi = lane >> 4;

  const __bf16* Ab = A + (size_t)(brow * BM) * GK;
  const __bf16* Bb = B + (size_t)(bcol * BN) * GK;
  const __bf16* Ab1 = Ab + (size_t)128 * GK;
  const __bf16* Bb1 = Bb + (size_t)128 * GK;

  // read-side swizzled chunk offsets (bytes within the 128-B row)
  int xr = lrow & 7;
  int offk0 = (lkhi ^ xr) * 16;        // kk=0 chunk
  int offk1 = ((4 + lkhi) ^ xr) * 16;  // kk=1 chunk
  const char* ldsc = (const char*)lds;
  // fragment byte bases within a buffer (regions: A0 0, A1 16K, B0 32K, B1 48K)
  int avbase = wm * 16384 + lrow * 128;                                // +mi*2048
  int bvbase = 32768 + (wn >> 1) * 16384 + ((wn & 1) * 64 + lrow) * 128;  // +ni*2048

  // stage-side: thread t writes bytes [t*16,t*16+16) of each 8-KiB half-region
  int grow = tid >> 3;                         // row within 64-row half
  int gcol = ((tid & 7) ^ (grow & 7)) * 8;     // pre-swizzled source col (elems)

  // stage ONE 128-row half-tile (2 x gload_lds) of K-step `kstep`
  auto STAGE = [&](const __bf16* srcbase, int kstep, int dstelem) {
    const __bf16* s = srcbase + (size_t)grow * GK + kstep * BK + gcol;
    const __bf16* d = lds + dstelem + tid * 8;
    gload16(s, d);
    gload16(s + (size_t)64 * GK, d + 4096);
  };

  f32x4 acc[8][4] = {};

  // prologue: step0 all 4 halves -> buf0; step1 {A0,B0,B1} -> buf1
  STAGE(Ab, 0, 0);
  STAGE(Ab1, 0, 8192);
  STAGE(Bb, 0, 16384);
  STAGE(Bb1, 0, 24576);
  STAGE(Ab, 1, 32768);        // buf1:A0
  STAGE(Bb, 1, 49152);        // buf1:B0
  STAGE(Bb1, 1, 57344);       // buf1:B1
  asm volatile("s_waitcnt vmcnt(6)" ::: "memory");  // step0 landed
  __builtin_amdgcn_s_barrier();

  for (int j = 0; j < IT; ++j) {
    int o = 2 * j + 1, n0 = 2 * j + 2, n1 = 2 * j + 3;
    bool full = (j < IT - 1);
    bf16x8 a0[4][2], a4[4][2], b0[2][2], b2[2][2];

    // ================= K-step 2j (buf0, byte 0) =================
    // P1: reads a0(8) + b0(4); stage (o):A1 -> buf1
#pragma unroll
    for (int mi = 0; mi < 4; ++mi) {
      a0[mi][0] = *(const bf16x8*)(ldsc + avbase + mi * 2048 + offk0);
      a0[mi][1] = *(const bf16x8*)(ldsc + avbase + mi * 2048 + offk1);
    }
#pragma unroll
    for (int ni = 0; ni < 2; ++ni) {
      b0[ni][0] = *(const bf16x8*)(ldsc + bvbase + ni * 2048 + offk0);
      b0[ni][1] = *(const bf16x8*)(ldsc + bvbase + ni * 2048 + offk1);
    }
    STAGE(Ab1, o, 40960);     // buf1:A1 (last read prev-iter P7; barrier-safe)
    asm volatile("s_waitcnt lgkmcnt(8)" ::: "memory");  // throttle 12-read burst
    PHASE_SYNC();
    QUAD(a0, b0, 0, 0);
    PHASE_END();

    // P2: reads b2(4)
#pragma unroll
    for (int ni = 0; ni < 2; ++ni) {
      b2[ni][0] = *(const bf16x8*)(ldsc + bvbase + (2 + ni) * 2048 + offk0);
      b2[ni][1] = *(const bf16x8*)(ldsc + bvbase + (2 + ni) * 2048 + offk1);
    }
    PHASE_SYNC();
    QUAD(a0, b2, 0, 2);
    PHASE_END();

    // P3: reads a4(8); stage (n0):B0,B1 -> buf0 (B last read P2)
#pragma unroll
    for (int mi = 0; mi < 4; ++mi) {
      a4[mi][0] = *(const bf16x8*)(ldsc + avbase + (4 + mi) * 2048 + offk0);
      a4[mi][1] = *(const bf16x8*)(ldsc + avbase + (4 + mi) * 2048 + offk1);
    }
    if (full) { STAGE(Bb, n0, 16384); STAGE(Bb1, n0, 24576); }
    PHASE_SYNC();
    QUAD(a4, b0, 4, 0);
    PHASE_END();

    // P4: stage (n0):A0 -> buf0 (A0 last read P3); vmcnt(6) retires step o
    if (full) STAGE(Ab, n0, 0);
    PHASE_SYNC();
    QUAD(a4, b2, 4, 2);
    __builtin_amdgcn_s_setprio(0);
    if (full) asm volatile("s_waitcnt vmcnt(6)" ::: "memory");
    else      asm volatile("s_waitcnt vmcnt(0)" ::: "memory");
    __builtin_amdgcn_s_barrier();

    // ================= K-step 2j+1 (buf1, byte 65536) =================
    // P5: reads a0(8) + b0(4); stage (n0):A1 -> buf0 (A1 last read P3)
#pragma unroll
    for (int mi = 0; mi < 4; ++mi) {
      a0[mi][0] = *(const bf16x8*)(ldsc + 65536 + avbase + mi * 2048 + offk0);
      a0[mi][1] = *(const bf16x8*)(ldsc + 65536 + avbase + mi * 2048 + offk1);
    }
#pragma unroll
    for (int ni = 0; ni < 2; ++ni) {
      b0[ni][0] = *(const bf16x8*)(ldsc + 65536 + bvbase + ni * 2048 + offk0);
      b0[ni][1] = *(const bf16x8*)(ldsc + 65536 + bvbase + ni * 2048 + offk1);
    }
    if (full) STAGE(Ab1, n0, 8192);
    asm volatile("s_waitcnt lgkmcnt(8)" ::: "memory");
    PHASE_SYNC();
    QUAD(a0, b0, 0, 0);
    PHASE_END();

    // P6: reads b2(4)
#pragma unroll
    for (int ni = 0; ni < 2; ++ni) {
      b2[ni][0] = *(const bf16x8*)(ldsc + 65536 + bvbase + (2 + ni) * 2048 + offk0);
      b2[ni][1] = *(const bf16x8*)(ldsc + 65536 + bvbase + (2 + ni) * 2048 + offk1);
    }
    PHASE_SYNC();
    QUAD(a0, b2, 0, 2);
    PHASE_END();

    // P7: reads a4(8); stage (n1):B0,B1 -> buf1 (B last read P6)
#pragma unroll
    for (int mi = 0; mi < 4; ++mi) {
      a4[mi][0] = *(const bf16x8*)(ldsc + 65536 + avbase + (4 + mi) * 2048 + offk0);
      a4[mi][1] = *(const bf16x8*)(ldsc + 65536 + avbase + (4 + mi) * 2048 + offk1);
    }
    if (full) { STAGE(Bb, n1, 49152); STAGE(Bb1, n1, 57344); }
    PHASE_SYNC();
    QUAD(a4, b0, 4, 0);
    PHASE_END();

    // P8: stage (n1):A0 -> buf1 (A0 last read P7); vmcnt(6) retires step n0
    if (full) STAGE(Ab, n1, 32768);
    PHASE_SYNC();
    QUAD(a4, b2, 4, 2);
    __builtin_amdgcn_s_setprio(0);
    if (full) asm volatile("s_waitcnt vmcnt(6)" ::: "memory");
    else      asm volatile("s_waitcnt vmcnt(0)" ::: "memory");
    __builtin_amdgcn_s_barrier();
  }

  // epilogue: h as bf16 into the second half of each f32 output row slot.
  // C/D layout (16x16x32 bf16): col = lane&15, row = (lane>>4)*4 + r
  int crow0 = brow * BM + wm * 128;
  int ccol0 = bcol * BN + wn * 64;
  char* Cb = (char*)C;
#pragma unroll
  for (int mi = 0; mi < 8; ++mi)
#pragma unroll
    for (int ni = 0; ni < 4; ++ni) {
      int col = ccol0 + ni * 16 + lrow;
#pragma unroll
      for (int r = 0; r < 4; ++r) {
        int row = crow0 + mi * 16 + lkhi * 4 + r;
        *(__bf16*)(Cb + (size_t)row * 16384 + 8192 + col * 2) =
            (__bf16)acc[mi][ni][r];
      }
    }
}

// ---------- fused out_scale/bias + LayerNorm: bf16 h (2nd half-slot) -> f32 ----------
__global__ __launch_bounds__(256) void ln_fuse(
    float* __restrict__ out, const float* __restrict__ os,
    const float* __restrict__ bs, const float* __restrict__ g,
    const float* __restrict__ be) {
  constexpr int N = GN;  // 4096
  int row = blockIdx.x;
  const __bf16* hr = (const __bf16*)((const char*)out + (size_t)row * 16384 + 8192);
  float* orow = out + (size_t)row * N;
  int t = threadIdx.x;

  float v[16];
  float sum = 0.f, ssq = 0.f;
#pragma unroll
  for (int c = 0; c < 2; ++c) {
    int idx = c * 2048 + t * 8;       // 8 bf16 per chunk, 2 chunks/thread
    bf16x8 hv = *(const bf16x8*)(hr + idx);
    float4 s0 = *(const float4*)(os + idx);
    float4 s1 = *(const float4*)(os + idx + 4);
    float4 b0 = *(const float4*)(bs + idx);
    float4 b1 = *(const float4*)(bs + idx + 4);
#pragma unroll
    for (int j = 0; j < 4; ++j) {
      float a = (float)hv[j] * (&s0.x)[j] + (&b0.x)[j];
      v[c * 8 + j] = a;
      sum += a; ssq += a * a;
    }
#pragma unroll
    for (int j = 0; j < 4; ++j) {
      float a = (float)hv[4 + j] * (&s1.x)[j] + (&b1.x)[j];
      v[c * 8 + 4 + j] = a;
      sum += a; ssq += a * a;
    }
  }

  // wave64 reduce
#pragma unroll
  for (int off = 32; off > 0; off >>= 1) {
    sum += __shfl_down(sum, off);
    ssq += __shfl_down(ssq, off);
  }
  __shared__ float rs[8];
  int wid = t >> 6, lane = t & 63;
  if (lane == 0) { rs[wid] = sum; rs[4 + wid] = ssq; }
  __syncthreads();   // also separates all h reads from the in-place writes
  sum = rs[0] + rs[1] + rs[2] + rs[3];
  ssq = rs[4] + rs[5] + rs[6] + rs[7];

  float mean = sum * (1.f / N);
  float var = ssq * (1.f / N) - mean * mean;
  float rstd = rsqrtf(var + 1e-5f);

#pragma unroll
  for (int c = 0; c < 2; ++c) {
    int idx = c * 2048 + t * 8;
    float4 g0 = *(const float4*)(g + idx);
    float4 g1 = *(const float4*)(g + idx + 4);
    float4 e0 = *(const float4*)(be + idx);
    float4 e1 = *(const float4*)(be + idx + 4);
    float4 o0, o1;
#pragma unroll
    for (int j = 0; j < 4; ++j) {
      (&o0.x)[j] = (v[c * 8 + j] - mean) * rstd * (&g0.x)[j] + (&e0.x)[j];
      (&o1.x)[j] = (v[c * 8 + 4 + j] - mean) * rstd * (&g1.x)[j] + (&e1.x)[j];
    }
    *(float4*)(orow + idx) = o0;
    *(float4*)(orow + idx + 4) = o1;
  }
}

extern "C" void kernel_launch(void* const* d_in, const int* in_sizes, int n_in,
                              void* d_out, int out_size, void* d_ws, size_t ws_size,
                              hipStream_t stream) {
  const float* x      = (const float*)d_in[0];  // [4,2048,4096]
  const float* w      = (const float*)d_in[1];  // [4096,4096]
  const float* iscale = (const float*)d_in[2];  // [4096]
  const float* oscale = (const float*)d_in[3];  // [4096]
  const float* bias   = (const float*)d_in[4];  // [4096]
  const float* gamma  = (const float*)d_in[5];  // [4096]
  const float* beta   = (const float*)d_in[6];  // [4096]
  float* out = (float*)d_out;                   // [8192,4096] f32

  __bf16* Abf = (__bf16*)d_ws;                                   // 67 MB
  __bf16* Wbf = (__bf16*)((char*)d_ws + (size_t)GM * GK * 2);    // 33.5 MB

  (void)hipFuncSetAttribute((const void*)gemm_bt,
                            hipFuncAttributeMaxDynamicSharedMemorySize, LDS_BYTES);

  prep_x_kernel<<<(GM * GK) / (256 * 8), 256, 0, stream>>>(x, iscale, Abf);
  prep_w_kernel<<<(GN * GK) / (256 * 8), 256, 0, stream>>>(w, Wbf);
  gemm_bt<<<(GM / BM) * (GN / BN), 512, LDS_BYTES, stream>>>(Abf, Wbf, out);
  ln_fuse<<<GM, 256, 0, stream>>>(out, oscale, bias, gamma, beta);
}